// Round 1
// baseline (45708.954 us; speedup 1.0000x reference)
//
#include <hip/hip_runtime.h>
#include <math.h>

#define DMODEL 768
#define HN 12
#define DHEAD 64
#define DFF 3072
#define VOC 30522
#define BB 8
#define SS 128
#define KW 4
#define TT 32

__device__ __forceinline__ float gelu_f(float x) {
    float x3 = x * x * x;
    return 0.5f * x * (1.0f + tanhf(0.7978845608028654f * (x + 0.044715f * x3)));
}

// ---- init tokens/scores ----
__global__ void init_k(int* tokens, float* scores) {
    int i = threadIdx.x;
    if (i < BB * KW) {
        tokens[i] = 101;                      // BOS
        scores[i] = (i & 3) ? -1e9f : 0.0f;
    }
}

// ---- h = emb[X] + pos[:S]; mb = (X!=0)?0:-1e9 ----
__global__ __launch_bounds__(256) void embed_enc(const int* __restrict__ X,
                                                 const float* __restrict__ emb,
                                                 const float* __restrict__ pos,
                                                 float* __restrict__ h,
                                                 float* __restrict__ mb) {
    int row = blockIdx.x;             // b*S + s
    int s = row & (SS - 1);
    int tok = X[row];
    const float* e = emb + (size_t)tok * DMODEL;
    const float* p = pos + (size_t)s * DMODEL;
    float* hp = h + (size_t)row * DMODEL;
    for (int c = threadIdx.x; c < DMODEL; c += 256) hp[c] = e[c] + p[c];
    if (threadIdx.x == 0) mb[row] = (tok != 0) ? 0.0f : -1e9f;
}

// ---- generic f32 GEMM: C[M,N] = A[M,K] @ B[K,N]; M,N %64==0, K %16==0 ----
__global__ __launch_bounds__(256) void gemm64(const float* __restrict__ A,
                                              const float* __restrict__ B,
                                              float* __restrict__ C,
                                              int M, int N, int Kd, int act) {
    __shared__ float As[16][68];
    __shared__ float Bs[16][68];
    int tid = threadIdx.x;
    int tx = tid & 15, ty = tid >> 4;
    int bm = blockIdx.y * 64, bn = blockIdx.x * 64;
    float acc[4][4] = {};
    for (int k0 = 0; k0 < Kd; k0 += 16) {
#pragma unroll
        for (int p = 0; p < 4; p++) {
            int idx = p * 256 + tid;
            int gk = idx & 15, gm = idx >> 4;
            As[gk][gm] = A[(size_t)(bm + gm) * Kd + k0 + gk];
        }
#pragma unroll
        for (int p = 0; p < 4; p++) {
            int idx = p * 256 + tid;
            int gn = idx & 63, gk = idx >> 6;
            Bs[gk][gn] = B[(size_t)(k0 + gk) * N + bn + gn];
        }
        __syncthreads();
#pragma unroll
        for (int kk = 0; kk < 16; kk++) {
            float4 a4 = *(const float4*)&As[kk][ty * 4];
            float4 b4 = *(const float4*)&Bs[kk][tx * 4];
            float av[4] = {a4.x, a4.y, a4.z, a4.w};
            float bv[4] = {b4.x, b4.y, b4.z, b4.w};
#pragma unroll
            for (int i = 0; i < 4; i++)
#pragma unroll
                for (int j = 0; j < 4; j++) acc[i][j] += av[i] * bv[j];
        }
        __syncthreads();
    }
#pragma unroll
    for (int i = 0; i < 4; i++)
#pragma unroll
        for (int j = 0; j < 4; j++) {
            float v = acc[i][j];
            if (act) v = gelu_f(v);
            C[(size_t)(bm + ty * 4 + i) * N + bn + tx * 4 + j] = v;
        }
}

// ---- encoder self-attention: one block (64 thr) per (b,h,q) ----
__global__ __launch_bounds__(64) void enc_attn(const float* __restrict__ q,
                                               const float* __restrict__ k,
                                               const float* __restrict__ v,
                                               const float* __restrict__ mb,
                                               float* __restrict__ ctx) {
    int bid = blockIdx.x;
    int qi = bid & (SS - 1);
    int h = (bid >> 7) % HN;
    int b = bid / (SS * HN);
    int lane = threadIdx.x;
    __shared__ float qs[DHEAD];
    __shared__ float att[SS];
    qs[lane] = q[((size_t)(b * SS + qi) * HN + h) * DHEAD + lane];
    __syncthreads();
    const float* kb = k + ((size_t)(b * SS) * HN + h) * DHEAD;
    const float* k0p = kb + (size_t)lane * DMODEL;
    const float* k1p = kb + (size_t)(lane + 64) * DMODEL;
    float s0 = 0.f, s1 = 0.f;
#pragma unroll 8
    for (int d = 0; d < DHEAD; d++) {
        float qd = qs[d];
        s0 += qd * k0p[d];
        s1 += qd * k1p[d];
    }
    s0 = s0 * 0.125f + mb[b * SS + lane];
    s1 = s1 * 0.125f + mb[b * SS + lane + 64];
    float m = fmaxf(s0, s1);
    for (int off = 32; off; off >>= 1) m = fmaxf(m, __shfl_xor(m, off, 64));
    float e0 = expf(s0 - m), e1 = expf(s1 - m);
    float sum = e0 + e1;
    for (int off = 32; off; off >>= 1) sum += __shfl_xor(sum, off, 64);
    float inv = 1.0f / sum;
    att[lane] = e0 * inv;
    att[lane + 64] = e1 * inv;
    __syncthreads();
    const float* vb = v + ((size_t)(b * SS) * HN + h) * DHEAD + lane;
    float acc = 0.f;
#pragma unroll 8
    for (int key = 0; key < SS; key++) acc += att[key] * vb[(size_t)key * DMODEL];
    ctx[(size_t)(b * SS + qi) * DMODEL + h * DHEAD + lane] = acc;
}

// ---- out = LN(A + Bsrc); optional transposed copy (32-row matrices only) ----
__global__ __launch_bounds__(256) void lnres(const float* __restrict__ A,
                                             const float* __restrict__ Bsrc,
                                             float* __restrict__ out,
                                             float* __restrict__ outT,
                                             int wantT) {
    int row = blockIdx.x, tid = threadIdx.x;
    const float* ap = A + (size_t)row * DMODEL;
    const float* bp = Bsrc + (size_t)row * DMODEL;
    float x[3];
#pragma unroll
    for (int i = 0; i < 3; i++) x[i] = ap[tid + 256 * i] + bp[tid + 256 * i];
    __shared__ float red[256];
    __shared__ float sm, sv;
    red[tid] = x[0] + x[1] + x[2];
    __syncthreads();
    for (int off = 128; off; off >>= 1) { if (tid < off) red[tid] += red[tid + off]; __syncthreads(); }
    if (tid == 0) sm = red[0] * (1.0f / DMODEL);
    __syncthreads();
    float mean = sm;
    float d[3], s2 = 0.f;
#pragma unroll
    for (int i = 0; i < 3; i++) { d[i] = x[i] - mean; s2 += d[i] * d[i]; }
    __syncthreads();
    red[tid] = s2;
    __syncthreads();
    for (int off = 128; off; off >>= 1) { if (tid < off) red[tid] += red[tid + off]; __syncthreads(); }
    if (tid == 0) sv = 1.0f / sqrtf(red[0] * (1.0f / DMODEL) + 1e-5f);
    __syncthreads();
    float inv = sv;
    float* op = out + (size_t)row * DMODEL;
#pragma unroll
    for (int i = 0; i < 3; i++) {
        float val = d[i] * inv;
        op[tid + 256 * i] = val;
        if (wantT) outT[(size_t)(tid + 256 * i) * 32 + row] = val;
    }
}

// ---- x = emb[tokens] + pos[t]; also xT ----
__global__ __launch_bounds__(256) void embed_dec(const int* __restrict__ tokens,
                                                 const float* __restrict__ emb,
                                                 const float* __restrict__ pos,
                                                 int t, float* __restrict__ x,
                                                 float* __restrict__ xT) {
    int row = blockIdx.x;   // 32
    int tok = tokens[row];
    const float* e = emb + (size_t)tok * DMODEL;
    const float* p = pos + (size_t)t * DMODEL;
    for (int c = threadIdx.x; c < DMODEL; c += 256) {
        float v = e[c] + p[c];
        x[(size_t)row * DMODEL + c] = v;
        xT[(size_t)c * 32 + row] = v;
    }
}

// ---- skinny GEMM: C[32,N] = At^T[32,Kd] @ B[Kd,N]; At is [Kd][32] ----
__global__ __launch_bounds__(256) void skinny(const float* __restrict__ At,
                                              const float* __restrict__ B,
                                              float* __restrict__ C,
                                              int Kd, int N, int act, int transOut) {
    int jl = threadIdx.x & 63;
    int q = threadIdx.x >> 6;
    int j = blockIdx.x * 64 + jl;
    int jc = j < N ? j : N - 1;
    int kchunk = Kd >> 2;
    int k0 = q * kchunk;
    float acc[32] = {};
    const float* Bp = B + jc;
    for (int k = k0; k < k0 + kchunk; k++) {
        float bv = Bp[(size_t)k * N];
        const float4* Ar = (const float4*)(At + (size_t)k * 32);
#pragma unroll
        for (int m4 = 0; m4 < 8; m4++) {
            float4 a = Ar[m4];
            acc[m4 * 4 + 0] += a.x * bv;
            acc[m4 * 4 + 1] += a.y * bv;
            acc[m4 * 4 + 2] += a.z * bv;
            acc[m4 * 4 + 3] += a.w * bv;
        }
    }
    __shared__ float red[4][8][64];
    for (int g = 0; g < 4; g++) {
#pragma unroll
        for (int mm = 0; mm < 8; mm++) red[q][mm][jl] = acc[g * 8 + mm];
        __syncthreads();
        for (int o = threadIdx.x; o < 512; o += 256) {
            int mm = o >> 6, jj = o & 63;
            int gj = blockIdx.x * 64 + jj;
            if (gj < N) {
                float s = red[0][mm][jj] + red[1][mm][jj] + red[2][mm][jj] + red[3][mm][jj];
                int m = g * 8 + mm;
                if (act) s = gelu_f(s);
                if (transOut) C[(size_t)gj * 32 + m] = s;
                else C[(size_t)m * N + gj] = s;
            }
        }
        __syncthreads();
    }
}

// ---- decoder cross-attention: block (64 thr) per (b,kbeam,h); writes cctxT ----
__global__ __launch_bounds__(64) void dec_attn(const float* __restrict__ qd,
                                               const float* __restrict__ Kmem,
                                               const float* __restrict__ Vmem,
                                               const float* __restrict__ mb,
                                               float* __restrict__ cctxT) {
    int bid = blockIdx.x;
    int h = bid % HN;
    int kb = (bid / HN) & 3;
    int b = bid / (HN * KW);
    int lane = threadIdx.x;
    int rowq = b * KW + kb;
    __shared__ float qs[DHEAD];
    __shared__ float att[SS];
    qs[lane] = qd[(size_t)rowq * DMODEL + h * DHEAD + lane];
    __syncthreads();
    const float* kb0 = Kmem + ((size_t)(b * SS) * HN + h) * DHEAD;
    const float* k0p = kb0 + (size_t)lane * DMODEL;
    const float* k1p = kb0 + (size_t)(lane + 64) * DMODEL;
    float s0 = 0.f, s1 = 0.f;
#pragma unroll 8
    for (int d = 0; d < DHEAD; d++) {
        float qv = qs[d];
        s0 += qv * k0p[d];
        s1 += qv * k1p[d];
    }
    s0 = s0 * 0.125f + mb[b * SS + lane];
    s1 = s1 * 0.125f + mb[b * SS + lane + 64];
    float m = fmaxf(s0, s1);
    for (int off = 32; off; off >>= 1) m = fmaxf(m, __shfl_xor(m, off, 64));
    float e0 = expf(s0 - m), e1 = expf(s1 - m);
    float sum = e0 + e1;
    for (int off = 32; off; off >>= 1) sum += __shfl_xor(sum, off, 64);
    float inv = 1.0f / sum;
    att[lane] = e0 * inv;
    att[lane + 64] = e1 * inv;
    __syncthreads();
    const float* vb = Vmem + ((size_t)(b * SS) * HN + h) * DHEAD + lane;
    float acc = 0.f;
#pragma unroll 8
    for (int key = 0; key < SS; key++) acc += att[key] * vb[(size_t)key * DMODEL];
    cctxT[(size_t)(h * DHEAD + lane) * 32 + rowq] = acc;
}

// ---- fused log_softmax + top-4 per batch; updates beams ----
__global__ __launch_bounds__(256) void topk_k(const float* __restrict__ logits,
                                              float* scores, int* tokens,
                                              int* beamh, int* tokh, int t) {
    int b = blockIdx.x;
    int tid = threadIdx.x;
    __shared__ float red[256];
    __shared__ int redi[256];
    __shared__ float slse[KW];
    __shared__ float s_old[KW];
    __shared__ int chosen[KW];
    __shared__ float chval[KW];
    if (tid < KW) s_old[tid] = scores[b * KW + tid];
    __syncthreads();
    for (int r = 0; r < KW; r++) {
        const float* row = logits + (size_t)(b * KW + r) * VOC;
        float m = -INFINITY;
        for (int i = tid; i < VOC; i += 256) m = fmaxf(m, row[i]);
        red[tid] = m;
        __syncthreads();
        for (int off = 128; off; off >>= 1) { if (tid < off) red[tid] = fmaxf(red[tid], red[tid + off]); __syncthreads(); }
        float mx = red[0];
        __syncthreads();
        float s = 0.f;
        for (int i = tid; i < VOC; i += 256) s += expf(row[i] - mx);
        red[tid] = s;
        __syncthreads();
        for (int off = 128; off; off >>= 1) { if (tid < off) red[tid] += red[tid + off]; __syncthreads(); }
        if (tid == 0) slse[r] = mx + logf(red[0]);
        __syncthreads();
    }
    for (int p = 0; p < KW; p++) {
        float bv = -INFINITY;
        int bi = 0x7fffffff;
        for (int r = 0; r < KW; r++) {
            float base = s_old[r] - slse[r];
            const float* row = logits + (size_t)(b * KW + r) * VOC;
            for (int i = tid; i < VOC; i += 256) {
                int idx = r * VOC + i;
                bool skip = false;
                for (int pp = 0; pp < p; pp++) skip |= (chosen[pp] == idx);
                float val = base + row[i];
                if (!skip && (val > bv || (val == bv && idx < bi))) { bv = val; bi = idx; }
            }
        }
        red[tid] = bv;
        redi[tid] = bi;
        __syncthreads();
        for (int off = 128; off; off >>= 1) {
            if (tid < off) {
                float v2 = red[tid + off];
                int i2 = redi[tid + off];
                if (v2 > red[tid] || (v2 == red[tid] && i2 < redi[tid])) { red[tid] = v2; redi[tid] = i2; }
            }
            __syncthreads();
        }
        if (tid == 0) { chosen[p] = redi[0]; chval[p] = red[0]; }
        __syncthreads();
    }
    if (tid < KW) {
        int idx = chosen[tid];
        int beam = idx / VOC;
        int tok = idx - beam * VOC;
        scores[b * KW + tid] = chval[tid];
        tokens[b * KW + tid] = tok;
        beamh[(t * BB + b) * KW + tid] = beam;
        tokh[(t * BB + b) * KW + tid] = tok;
    }
}

// ---- backtrack through back-pointers; write seq (as float) + final scores ----
__global__ void backtrack_k(const int* __restrict__ beamh, const int* __restrict__ tokh,
                            const float* __restrict__ scores, float* __restrict__ out) {
    int i = threadIdx.x;
    if (i < BB * KW) {
        int b = i >> 2, k = i & 3;
        int ptr = k;
        for (int t = TT - 1; t >= 0; t--) {
            int tok = tokh[(t * BB + b) * KW + ptr];
            out[(size_t)i * TT + t] = (float)tok;
            ptr = beamh[(t * BB + b) * KW + ptr];
        }
        out[BB * KW * TT + i] = scores[i];
    }
}

extern "C" void kernel_launch(void* const* d_in, const int* in_sizes, int n_in,
                              void* d_out, int out_size, void* d_ws, size_t ws_size,
                              hipStream_t stream) {
    const int* X = (const int*)d_in[0];
    const float* emb = (const float*)d_in[1];
    const float* pos = (const float*)d_in[2];
    const float* Wq = (const float*)d_in[3];
    const float* Wk = (const float*)d_in[4];
    const float* Wv = (const float*)d_in[5];
    const float* Wo = (const float*)d_in[6];
    const float* W1 = (const float*)d_in[7];
    const float* W2 = (const float*)d_in[8];
    const float* Wdq = (const float*)d_in[9];
    const float* Wdk = (const float*)d_in[10];
    const float* Wdv = (const float*)d_in[11];
    const float* Wdo = (const float*)d_in[12];
    const float* Wd1 = (const float*)d_in[13];
    const float* Wd2 = (const float*)d_in[14];
    const float* Wvoc = (const float*)d_in[15];

    float* ws = (float*)d_ws;
    size_t o = 0;
    auto alloc = [&](size_t n) { float* p = ws + o; o += n; return p; };

    const size_t ROWS = (size_t)BB * SS;       // 1024
    const size_t HD = ROWS * DMODEL;           // 786432

    // persistent
    float* mb = alloc(ROWS);
    float* mem = alloc(HD);
    float* Kmem = alloc(HD);
    float* Vmem = alloc(HD);
    float* scores = alloc(32);
    int* tokens = (int*)alloc(32);
    int* beamh = (int*)alloc(TT * BB * KW);
    int* tokh = (int*)alloc(TT * BB * KW);

    size_t mark = o;
    // encoder scratch
    float* h0 = alloc(HD);
    float* qb = alloc(HD);
    float* kb = alloc(HD);
    float* vb = alloc(HD);
    float* attc = alloc(HD);
    float* attp = alloc(HD);
    float* h1 = alloc(HD);
    float* ff1 = alloc(ROWS * DFF);
    float* ff2 = alloc(HD);

    // decoder scratch (aliases encoder scratch region)
    o = mark;
    float* logits = alloc((size_t)BB * KW * VOC);
    float* x = alloc(32 * DMODEL);
    float* xT = alloc(32 * DMODEL);
    float* qd = alloc(32 * DMODEL);
    float* cctxT = alloc(32 * DMODEL);
    float* cproj = alloc(32 * DMODEL);
    float* hd1 = alloc(32 * DMODEL);
    float* hd1T = alloc(32 * DMODEL);
    float* dff1T = alloc((size_t)32 * DFF);
    float* dff2 = alloc(32 * DMODEL);
    float* hd2 = alloc(32 * DMODEL);
    float* hd2T = alloc(32 * DMODEL);
    (void)ws_size; (void)in_sizes; (void)n_in; (void)out_size;

    init_k<<<1, 64, 0, stream>>>(tokens, scores);

    // ---- encoder ----
    embed_enc<<<dim3(ROWS), 256, 0, stream>>>(X, emb, pos, h0, mb);
    dim3 g768(DMODEL / 64, ROWS / 64);
    dim3 g3072(DFF / 64, ROWS / 64);
    gemm64<<<g768, 256, 0, stream>>>(h0, Wq, qb, ROWS, DMODEL, DMODEL, 0);
    gemm64<<<g768, 256, 0, stream>>>(h0, Wk, kb, ROWS, DMODEL, DMODEL, 0);
    gemm64<<<g768, 256, 0, stream>>>(h0, Wv, vb, ROWS, DMODEL, DMODEL, 0);
    enc_attn<<<dim3(BB * HN * SS), 64, 0, stream>>>(qb, kb, vb, mb, attc);
    gemm64<<<g768, 256, 0, stream>>>(attc, Wo, attp, ROWS, DMODEL, DMODEL, 0);
    lnres<<<dim3(ROWS), 256, 0, stream>>>(h0, attp, h1, nullptr, 0);
    gemm64<<<g3072, 256, 0, stream>>>(h1, W1, ff1, ROWS, DFF, DMODEL, 1);
    gemm64<<<g768, 256, 0, stream>>>(ff1, W2, ff2, ROWS, DMODEL, DFF, 0);
    lnres<<<dim3(ROWS), 256, 0, stream>>>(h1, ff2, mem, nullptr, 0);
    gemm64<<<g768, 256, 0, stream>>>(mem, Wdk, Kmem, ROWS, DMODEL, DMODEL, 0);
    gemm64<<<g768, 256, 0, stream>>>(mem, Wdv, Vmem, ROWS, DMODEL, DMODEL, 0);

    // ---- beam search decode ----
    for (int t = 0; t < TT; t++) {
        embed_dec<<<dim3(32), 256, 0, stream>>>(tokens, emb, pos, t, x, xT);
        skinny<<<dim3(DMODEL / 64), 256, 0, stream>>>(xT, Wdq, qd, DMODEL, DMODEL, 0, 0);
        dec_attn<<<dim3(BB * KW * HN), 64, 0, stream>>>(qd, Kmem, Vmem, mb, cctxT);
        skinny<<<dim3(DMODEL / 64), 256, 0, stream>>>(cctxT, Wdo, cproj, DMODEL, DMODEL, 0, 0);
        lnres<<<dim3(32), 256, 0, stream>>>(x, cproj, hd1, hd1T, 1);
        skinny<<<dim3(DFF / 64), 256, 0, stream>>>(hd1T, Wd1, dff1T, DMODEL, DFF, 1, 1);
        skinny<<<dim3(DMODEL / 64), 256, 0, stream>>>(dff1T, Wd2, dff2, DFF, DMODEL, 0, 0);
        lnres<<<dim3(32), 256, 0, stream>>>(hd1, dff2, hd2, hd2T, 1);
        skinny<<<dim3((VOC + 63) / 64), 256, 0, stream>>>(hd2T, Wvoc, logits, DMODEL, VOC, 0, 0);
        topk_k<<<dim3(BB), 256, 0, stream>>>(logits, scores, tokens, beamh, tokh, t);
    }

    backtrack_k<<<1, 64, 0, stream>>>(beamh, tokh, scores, (float*)d_out);
}

// Round 2
// 14138.986 us; speedup vs baseline: 3.2328x; 3.2328x over previous
//
#include <hip/hip_runtime.h>
#include <math.h>

#define DMODEL 768
#define HN 12
#define DHEAD 64
#define DFF 3072
#define VOC 30522
#define BB 8
#define SS 128
#define KW 4
#define TT 32
#define CHN 477   // ceil(30522/64)

__device__ __forceinline__ float gelu_f(float x) {
    float x3 = x * x * x;
    return 0.5f * x * (1.0f + tanhf(0.7978845608028654f * (x + 0.044715f * x3)));
}

// ---- init tokens/scores ----
__global__ void init_k(int* tokens, float* scores) {
    int i = threadIdx.x;
    if (i < BB * KW) {
        tokens[i] = 101;                      // BOS
        scores[i] = (i & 3) ? -1e9f : 0.0f;
    }
}

// ---- h = emb[X] + pos[:S]; mb = (X!=0)?0:-1e9 ----
__global__ __launch_bounds__(256) void embed_enc(const int* __restrict__ X,
                                                 const float* __restrict__ emb,
                                                 const float* __restrict__ pos,
                                                 float* __restrict__ h,
                                                 float* __restrict__ mb) {
    int row = blockIdx.x;
    int s = row & (SS - 1);
    int tok = X[row];
    const float* e = emb + (size_t)tok * DMODEL;
    const float* p = pos + (size_t)s * DMODEL;
    float* hp = h + (size_t)row * DMODEL;
    for (int c = threadIdx.x; c < DMODEL; c += 256) hp[c] = e[c] + p[c];
    if (threadIdx.x == 0) mb[row] = (tok != 0) ? 0.0f : -1e9f;
}

// ---- f32 GEMM 64x64 tile, register-prefetch double-buffered staging ----
template<int KD, int ACT>
__global__ __launch_bounds__(256) void gemm64(const float* __restrict__ A,
                                              const float* __restrict__ B,
                                              float* __restrict__ C, int N) {
    __shared__ float As[16][68];
    __shared__ float Bs[16][68];
    int tid = threadIdx.x;
    int tx = tid & 15, ty = tid >> 4;
    int bm = blockIdx.y * 64, bn = blockIdx.x * 64;
    int a_gk = tid & 15, a_gm0 = tid >> 4;
    int b_gn = tid & 63, b_gk0 = tid >> 6;
    float ra[4], rb[4];
    float acc[4][4] = {};
#pragma unroll
    for (int p = 0; p < 4; p++) ra[p] = A[(size_t)(bm + a_gm0 + p * 16) * KD + a_gk];
#pragma unroll
    for (int p = 0; p < 4; p++) rb[p] = B[(size_t)(b_gk0 + p * 4) * N + bn + b_gn];
    for (int k0 = 0; k0 < KD; k0 += 16) {
        __syncthreads();
#pragma unroll
        for (int p = 0; p < 4; p++) As[a_gk][a_gm0 + p * 16] = ra[p];
#pragma unroll
        for (int p = 0; p < 4; p++) Bs[b_gk0 + p * 4][b_gn] = rb[p];
        __syncthreads();
        if (k0 + 16 < KD) {
#pragma unroll
            for (int p = 0; p < 4; p++) ra[p] = A[(size_t)(bm + a_gm0 + p * 16) * KD + k0 + 16 + a_gk];
#pragma unroll
            for (int p = 0; p < 4; p++) rb[p] = B[(size_t)(k0 + 16 + b_gk0 + p * 4) * N + bn + b_gn];
        }
#pragma unroll
        for (int kk = 0; kk < 16; kk++) {
            float4 a4 = *(const float4*)&As[kk][ty * 4];
            float4 b4 = *(const float4*)&Bs[kk][tx * 4];
            float av[4] = {a4.x, a4.y, a4.z, a4.w};
            float bv[4] = {b4.x, b4.y, b4.z, b4.w};
#pragma unroll
            for (int i = 0; i < 4; i++)
#pragma unroll
                for (int j = 0; j < 4; j++) acc[i][j] += av[i] * bv[j];
        }
    }
#pragma unroll
    for (int i = 0; i < 4; i++)
#pragma unroll
        for (int j = 0; j < 4; j++) {
            float v = acc[i][j];
            if (ACT) v = gelu_f(v);
            C[(size_t)(bm + ty * 4 + i) * N + bn + tx * 4 + j] = v;
        }
}

// ---- encoder self-attention: one block (64 thr) per (b,h,q) ----
__global__ __launch_bounds__(64) void enc_attn(const float* __restrict__ q,
                                               const float* __restrict__ k,
                                               const float* __restrict__ v,
                                               const float* __restrict__ mb,
                                               float* __restrict__ ctx) {
    int bid = blockIdx.x;
    int qi = bid & (SS - 1);
    int h = (bid >> 7) % HN;
    int b = bid / (SS * HN);
    int lane = threadIdx.x;
    __shared__ float qs[DHEAD];
    __shared__ float att[SS];
    qs[lane] = q[((size_t)(b * SS + qi) * HN + h) * DHEAD + lane];
    __syncthreads();
    const float* kb = k + ((size_t)(b * SS) * HN + h) * DHEAD;
    const float* k0p = kb + (size_t)lane * DMODEL;
    const float* k1p = kb + (size_t)(lane + 64) * DMODEL;
    float s0 = 0.f, s1 = 0.f;
#pragma unroll 8
    for (int d = 0; d < DHEAD; d++) {
        float qd = qs[d];
        s0 += qd * k0p[d];
        s1 += qd * k1p[d];
    }
    s0 = s0 * 0.125f + mb[b * SS + lane];
    s1 = s1 * 0.125f + mb[b * SS + lane + 64];
    float m = fmaxf(s0, s1);
    for (int off = 32; off; off >>= 1) m = fmaxf(m, __shfl_xor(m, off, 64));
    float e0 = expf(s0 - m), e1 = expf(s1 - m);
    float sum = e0 + e1;
    for (int off = 32; off; off >>= 1) sum += __shfl_xor(sum, off, 64);
    float inv = 1.0f / sum;
    att[lane] = e0 * inv;
    att[lane + 64] = e1 * inv;
    __syncthreads();
    const float* vb = v + ((size_t)(b * SS) * HN + h) * DHEAD + lane;
    float acc = 0.f;
#pragma unroll 8
    for (int key = 0; key < SS; key++) acc += att[key] * vb[(size_t)key * DMODEL];
    ctx[(size_t)(b * SS + qi) * DMODEL + h * DHEAD + lane] = acc;
}

// ---- out = LN(A + sum_p Bsrc[p]); optional transposed copy (32-row only) ----
template<int P>
__global__ __launch_bounds__(256) void lnresP(const float* __restrict__ A,
                                              const float* __restrict__ Bsrc,
                                              float* __restrict__ out,
                                              float* __restrict__ outT,
                                              int wantT, int planeStride) {
    int row = blockIdx.x, tid = threadIdx.x;
    const float* ap = A + (size_t)row * DMODEL;
    float x[3];
#pragma unroll
    for (int i = 0; i < 3; i++) {
        int idx = tid + 256 * i;
        float s = ap[idx];
#pragma unroll
        for (int p = 0; p < P; p++) s += Bsrc[(size_t)p * planeStride + (size_t)row * DMODEL + idx];
        x[i] = s;
    }
    __shared__ float red[256];
    __shared__ float sm, sv;
    red[tid] = x[0] + x[1] + x[2];
    __syncthreads();
    for (int off = 128; off; off >>= 1) { if (tid < off) red[tid] += red[tid + off]; __syncthreads(); }
    if (tid == 0) sm = red[0] * (1.0f / DMODEL);
    __syncthreads();
    float mean = sm;
    float d[3], s2 = 0.f;
#pragma unroll
    for (int i = 0; i < 3; i++) { d[i] = x[i] - mean; s2 += d[i] * d[i]; }
    __syncthreads();
    red[tid] = s2;
    __syncthreads();
    for (int off = 128; off; off >>= 1) { if (tid < off) red[tid] += red[tid + off]; __syncthreads(); }
    if (tid == 0) sv = 1.0f / sqrtf(red[0] * (1.0f / DMODEL) + 1e-5f);
    __syncthreads();
    float inv = sv;
    float* op = out + (size_t)row * DMODEL;
#pragma unroll
    for (int i = 0; i < 3; i++) {
        float val = d[i] * inv;
        op[tid + 256 * i] = val;
        if (wantT) outT[(size_t)(tid + 256 * i) * 32 + row] = val;
    }
}

// ---- x = emb[tokens] + pos[t]; also xT ----
__global__ __launch_bounds__(256) void embed_dec(const int* __restrict__ tokens,
                                                 const float* __restrict__ emb,
                                                 const float* __restrict__ pos,
                                                 int t, float* __restrict__ x,
                                                 float* __restrict__ xT) {
    int row = blockIdx.x;
    int tok = tokens[row];
    const float* e = emb + (size_t)tok * DMODEL;
    const float* p = pos + (size_t)t * DMODEL;
    for (int c = threadIdx.x; c < DMODEL; c += 256) {
        float v = e[c] + p[c];
        x[(size_t)row * DMODEL + c] = v;
        xT[(size_t)c * 32 + row] = v;
    }
}

// ---- skinny GEMM: Cpart[by][32,N] (+= not; write) = At^T chunk @ B chunk ----
// At layout [Kd][32]; block covers rows kbase0=by*KRANGE..+KRANGE, staged in LDS.
template<int KRANGE, int ACT, int TOUT>
__global__ __launch_bounds__(256) void skinny2(const float* __restrict__ At,
                                               const float* __restrict__ B,
                                               float* __restrict__ C, int N) {
    constexpr int SK = 192;
    constexpr int NST = KRANGE / SK;
    __shared__ float Als[SK * 32];        // 24 KB
    __shared__ float red[4][8][64];       // 8 KB
    int tid = threadIdx.x;
    int jl = tid & 63, q = tid >> 6;
    int j = blockIdx.x * 64 + jl;
    int kbase0 = blockIdx.y * KRANGE;
    float acc[32] = {};
    for (int st = 0; st < NST; st++) {
        int kbase = kbase0 + st * SK;
        __syncthreads();
        const float4* src = (const float4*)(At + (size_t)kbase * 32);
        float4* dst = (float4*)Als;
#pragma unroll
        for (int i = 0; i < 6; i++) dst[i * 256 + tid] = src[i * 256 + tid];
        __syncthreads();
        const float* Bp = B + (size_t)(kbase + q * (SK / 4)) * N + j;
        const float* Ap = Als + (q * (SK / 4)) * 32;
#pragma unroll 4
        for (int k = 0; k < SK / 4; k++) {
            float bv = Bp[(size_t)k * N];
            const float4* Ar = (const float4*)(Ap + k * 32);
#pragma unroll
            for (int m4 = 0; m4 < 8; m4++) {
                float4 a = Ar[m4];
                acc[m4 * 4 + 0] += a.x * bv;
                acc[m4 * 4 + 1] += a.y * bv;
                acc[m4 * 4 + 2] += a.z * bv;
                acc[m4 * 4 + 3] += a.w * bv;
            }
        }
    }
    float* Cb = C + (size_t)blockIdx.y * 32 * N;
    for (int g = 0; g < 4; g++) {
        __syncthreads();
#pragma unroll
        for (int mm = 0; mm < 8; mm++) red[q][mm][jl] = acc[g * 8 + mm];
        __syncthreads();
        for (int o = tid; o < 512; o += 256) {
            int mm = o >> 6, jj = o & 63;
            int gj = blockIdx.x * 64 + jj;
            float s = red[0][mm][jj] + red[1][mm][jj] + red[2][mm][jj] + red[3][mm][jj];
            int m = g * 8 + mm;
            if (ACT) s = gelu_f(s);
            if (TOUT) Cb[(size_t)gj * 32 + m] = s;
            else      Cb[(size_t)m * N + gj] = s;
        }
    }
}

// ---- decoder cross-attn; qd given as 4 k-split partial planes ----
__global__ __launch_bounds__(64) void dec_attn(const float* __restrict__ qdp,
                                               const float* __restrict__ Kmem,
                                               const float* __restrict__ Vmem,
                                               const float* __restrict__ mb,
                                               float* __restrict__ cctxT) {
    const int QP = 32 * DMODEL;
    int bid = blockIdx.x;
    int h = bid % HN;
    int kb = (bid / HN) & 3;
    int b = bid / (HN * KW);
    int lane = threadIdx.x;
    int rowq = b * KW + kb;
    __shared__ float qs[DHEAD];
    __shared__ float att[SS];
    size_t qoff = (size_t)rowq * DMODEL + h * DHEAD + lane;
    qs[lane] = qdp[qoff] + qdp[QP + qoff] + qdp[2 * QP + qoff] + qdp[3 * QP + qoff];
    __syncthreads();
    const float* kb0 = Kmem + ((size_t)(b * SS) * HN + h) * DHEAD;
    const float* k0p = kb0 + (size_t)lane * DMODEL;
    const float* k1p = kb0 + (size_t)(lane + 64) * DMODEL;
    float s0 = 0.f, s1 = 0.f;
#pragma unroll 8
    for (int d = 0; d < DHEAD; d++) {
        float qv = qs[d];
        s0 += qv * k0p[d];
        s1 += qv * k1p[d];
    }
    s0 = s0 * 0.125f + mb[b * SS + lane];
    s1 = s1 * 0.125f + mb[b * SS + lane + 64];
    float m = fmaxf(s0, s1);
    for (int off = 32; off; off >>= 1) m = fmaxf(m, __shfl_xor(m, off, 64));
    float e0 = expf(s0 - m), e1 = expf(s1 - m);
    float sum = e0 + e1;
    for (int off = 32; off; off >>= 1) sum += __shfl_xor(sum, off, 64);
    float inv = 1.0f / sum;
    att[lane] = e0 * inv;
    att[lane + 64] = e1 * inv;
    __syncthreads();
    const float* vb = Vmem + ((size_t)(b * SS) * HN + h) * DHEAD + lane;
    float acc = 0.f;
#pragma unroll 8
    for (int key = 0; key < SS; key++) acc += att[key] * vb[(size_t)key * DMODEL];
    cctxT[(size_t)(h * DHEAD + lane) * 32 + rowq] = acc;
}

// ---- logits chunk kernel: GEMM (32 x 64cols) + per-row chunk stats, no global logits ----
__global__ __launch_bounds__(256) void logits_stats(const float* __restrict__ At,   // hd2T [768][32]
                                                    const float* __restrict__ B,    // Wvoc
                                                    float* __restrict__ cmax,
                                                    float* __restrict__ csum,
                                                    float* __restrict__ ctv,
                                                    int* __restrict__ cti) {
    constexpr int SK = 192, NST = 4;
    __shared__ float Als[SK * 32];
    __shared__ float red[4][8][64];
    __shared__ float Ct[32][72];
    int tid = threadIdx.x;
    int jl = tid & 63, q = tid >> 6;
    int j = blockIdx.x * 64 + jl;
    int jc = j < VOC ? j : VOC - 1;
    float acc[32] = {};
    for (int st = 0; st < NST; st++) {
        int kbase = st * SK;
        __syncthreads();
        const float4* src = (const float4*)(At + (size_t)kbase * 32);
        float4* dst = (float4*)Als;
#pragma unroll
        for (int i = 0; i < 6; i++) dst[i * 256 + tid] = src[i * 256 + tid];
        __syncthreads();
        const float* Bp = B + (size_t)(kbase + q * 48) * VOC + jc;
        const float* Ap = Als + (q * 48) * 32;
#pragma unroll 4
        for (int k = 0; k < 48; k++) {
            float bv = Bp[(size_t)k * VOC];
            const float4* Ar = (const float4*)(Ap + k * 32);
#pragma unroll
            for (int m4 = 0; m4 < 8; m4++) {
                float4 a = Ar[m4];
                acc[m4 * 4 + 0] += a.x * bv;
                acc[m4 * 4 + 1] += a.y * bv;
                acc[m4 * 4 + 2] += a.z * bv;
                acc[m4 * 4 + 3] += a.w * bv;
            }
        }
    }
    for (int g = 0; g < 4; g++) {
        __syncthreads();
#pragma unroll
        for (int mm = 0; mm < 8; mm++) red[q][mm][jl] = acc[g * 8 + mm];
        __syncthreads();
        for (int o = tid; o < 512; o += 256) {
            int mm = o >> 6, jj = o & 63;
            Ct[g * 8 + mm][jj] = red[0][mm][jj] + red[1][mm][jj] + red[2][mm][jj] + red[3][mm][jj];
        }
    }
    __syncthreads();
    // stats: wave q handles rows q*8..q*8+7; lane = col within chunk
    int lane = jl;
    int colg = blockIdx.x * 64 + lane;
    bool valid = colg < VOC;
#pragma unroll 1
    for (int rr = 0; rr < 8; rr++) {
        int m = q * 8 + rr;
        float v = valid ? Ct[m][lane] : -INFINITY;
        float mx = v;
#pragma unroll
        for (int off = 32; off; off >>= 1) mx = fmaxf(mx, __shfl_xor(mx, off, 64));
        float ss = valid ? expf(v - mx) : 0.0f;
#pragma unroll
        for (int off = 32; off; off >>= 1) ss += __shfl_xor(ss, off, 64);
        float cv = v; int ci = colg;
        float tv[4]; int tiv[4];
#pragma unroll
        for (int p = 0; p < 4; p++) {
            float bv = cv; int bi = ci;
#pragma unroll
            for (int off = 32; off; off >>= 1) {
                float ov = __shfl_xor(bv, off, 64);
                int oi = __shfl_xor(bi, off, 64);
                if (ov > bv || (ov == bv && oi < bi)) { bv = ov; bi = oi; }
            }
            tv[p] = bv; tiv[p] = bi;
            if (ci == bi) cv = -INFINITY;
        }
        if (lane == 0) {
            int o = m * CHN + blockIdx.x;
            cmax[o] = mx; csum[o] = ss;
            ctv[o * 4 + 0] = tv[0]; cti[o * 4 + 0] = tiv[0];
            ctv[o * 4 + 1] = tv[1]; cti[o * 4 + 1] = tiv[1];
            ctv[o * 4 + 2] = tv[2]; cti[o * 4 + 2] = tiv[2];
            ctv[o * 4 + 3] = tv[3]; cti[o * 4 + 3] = tiv[3];
        }
    }
}

// ---- merge chunk stats: LSE per beam, per-beam top4, cross-beam top4, update ----
__global__ __launch_bounds__(256) void merge_topk(const float* __restrict__ cmax,
                                                  const float* __restrict__ csum,
                                                  const float* __restrict__ ctv,
                                                  const int* __restrict__ cti,
                                                  float* scores, int* tokens,
                                                  int* beamh, int* tokh, int t) {
    int b = blockIdx.x, tid = threadIdx.x;
    __shared__ float rv[256];
    __shared__ float rs[256];
    __shared__ int ri[256];
    __shared__ float LSE[4], s_old[4];
    __shared__ float bt_v[4][4];
    __shared__ int bt_i[4][4];
    __shared__ int chosen[4];
    if (tid < 4) s_old[tid] = scores[b * 4 + tid];
    for (int r = 0; r < 4; r++) {
        int m = b * 4 + r;
        float mx = -INFINITY, sm = 0.f;
        for (int c = tid; c < CHN; c += 256) {
            float cm = cmax[m * CHN + c], cs = csum[m * CHN + c];
            if (cm > mx) { sm = sm * expf(mx - cm) + cs; mx = cm; }
            else sm += cs * expf(cm - mx);
        }
        rv[tid] = mx; rs[tid] = sm;
        __syncthreads();
        for (int off = 128; off; off >>= 1) {
            if (tid < off) {
                float m1 = rv[tid], s1 = rs[tid];
                float m2 = rv[tid + off], s2 = rs[tid + off];
                float M = fmaxf(m1, m2);
                rv[tid] = M;
                rs[tid] = s1 * expf(m1 - M) + s2 * expf(m2 - M);
            }
            __syncthreads();
        }
        if (tid == 0) LSE[r] = rv[0] + logf(rs[0]);
        __syncthreads();
    }
    for (int r = 0; r < 4; r++) {
        int m = b * 4 + r;
        for (int p = 0; p < 4; p++) {
            float bv = -INFINITY; int bi = 0x7fffffff;
            for (int c = tid; c < CHN; c += 256) {
                int o = (m * CHN + c) * 4;
#pragma unroll
                for (int qq = 0; qq < 4; qq++) {
                    float v = ctv[o + qq]; int i = cti[o + qq];
                    bool skip = false;
                    for (int pp = 0; pp < p; pp++) skip |= (chosen[pp] == i);
                    if (!skip && (v > bv || (v == bv && i < bi))) { bv = v; bi = i; }
                }
            }
            rv[tid] = bv; ri[tid] = bi;
            __syncthreads();
            for (int off = 128; off; off >>= 1) {
                if (tid < off) {
                    float v2 = rv[tid + off]; int i2 = ri[tid + off];
                    if (v2 > rv[tid] || (v2 == rv[tid] && i2 < ri[tid])) { rv[tid] = v2; ri[tid] = i2; }
                }
                __syncthreads();
            }
            if (tid == 0) { chosen[p] = ri[0]; bt_v[r][p] = rv[0]; bt_i[r][p] = ri[0]; }
            __syncthreads();
        }
    }
    if (tid == 0) {
        float fv[16]; int fi[16]; bool used[16];
        for (int r = 0; r < 4; r++)
            for (int p = 0; p < 4; p++) {
                fv[r * 4 + p] = s_old[r] - LSE[r] + bt_v[r][p];
                fi[r * 4 + p] = r * VOC + bt_i[r][p];
                used[r * 4 + p] = false;
            }
        for (int kk = 0; kk < 4; kk++) {
            int best = -1;
            for (int c2 = 0; c2 < 16; c2++) {
                if (used[c2]) continue;
                if (best < 0 || fv[c2] > fv[best] || (fv[c2] == fv[best] && fi[c2] < fi[best])) best = c2;
            }
            used[best] = true;
            int beam = fi[best] / VOC;
            int tok = fi[best] - beam * VOC;
            scores[b * 4 + kk] = fv[best];
            tokens[b * 4 + kk] = tok;
            beamh[(t * BB + b) * 4 + kk] = beam;
            tokh[(t * BB + b) * 4 + kk] = tok;
        }
    }
}

// ---- backtrack ----
__global__ void backtrack_k(const int* __restrict__ beamh, const int* __restrict__ tokh,
                            const float* __restrict__ scores, float* __restrict__ out) {
    int i = threadIdx.x;
    if (i < BB * KW) {
        int b = i >> 2, k = i & 3;
        int ptr = k;
        for (int t = TT - 1; t >= 0; t--) {
            int tok = tokh[(t * BB + b) * KW + ptr];
            out[(size_t)i * TT + t] = (float)tok;
            ptr = beamh[(t * BB + b) * KW + ptr];
        }
        out[BB * KW * TT + i] = scores[i];
    }
}

extern "C" void kernel_launch(void* const* d_in, const int* in_sizes, int n_in,
                              void* d_out, int out_size, void* d_ws, size_t ws_size,
                              hipStream_t stream) {
    const int* X = (const int*)d_in[0];
    const float* emb = (const float*)d_in[1];
    const float* pos = (const float*)d_in[2];
    const float* Wq = (const float*)d_in[3];
    const float* Wk = (const float*)d_in[4];
    const float* Wv = (const float*)d_in[5];
    const float* Wo = (const float*)d_in[6];
    const float* W1 = (const float*)d_in[7];
    const float* W2 = (const float*)d_in[8];
    const float* Wdq = (const float*)d_in[9];
    const float* Wdk = (const float*)d_in[10];
    const float* Wdv = (const float*)d_in[11];
    const float* Wdo = (const float*)d_in[12];
    const float* Wd1 = (const float*)d_in[13];
    const float* Wd2 = (const float*)d_in[14];
    const float* Wvoc = (const float*)d_in[15];

    float* ws = (float*)d_ws;
    size_t o = 0;
    auto alloc = [&](size_t n) { float* p = ws + o; o += n; return p; };

    const size_t ROWS = (size_t)BB * SS;       // 1024
    const size_t HD = ROWS * DMODEL;
    const size_t P32 = 32 * DMODEL;

    // persistent
    float* mb = alloc(ROWS);
    float* Kmem = alloc(HD);
    float* Vmem = alloc(HD);
    float* scores = alloc(32);
    int* tokens = (int*)alloc(32);
    int* beamh = (int*)alloc(TT * BB * KW);
    int* tokh = (int*)alloc(TT * BB * KW);

    size_t mark = o;
    // encoder scratch
    float* h0 = alloc(HD);
    float* qb = alloc(HD);
    float* kb = alloc(HD);
    float* vb = alloc(HD);
    float* attc = alloc(HD);
    float* attp = alloc(HD);
    float* h1 = alloc(HD);
    float* ff1 = alloc(ROWS * DFF);
    float* ff2 = alloc(HD);
    float* memb = alloc(HD);

    // decoder scratch (aliases encoder scratch)
    o = mark;
    float* x = alloc(P32);
    float* xT = alloc(P32);
    float* qdp = alloc(4 * P32);
    float* cctxT = alloc(P32);
    float* cprojp = alloc(4 * P32);
    float* hd1 = alloc(P32);
    float* hd1T = alloc(P32);
    float* dff1T = alloc((size_t)32 * DFF);
    float* dff2p = alloc(4 * P32);
    float* hd2 = alloc(P32);
    float* hd2T = alloc(P32);
    float* cmax = alloc(32 * CHN);
    float* csum = alloc(32 * CHN);
    float* ctv = alloc((size_t)32 * CHN * 4);
    int* cti = (int*)alloc((size_t)32 * CHN * 4);
    (void)ws_size; (void)in_sizes; (void)n_in; (void)out_size;

    init_k<<<1, 64, 0, stream>>>(tokens, scores);

    // ---- encoder ----
    embed_enc<<<dim3(ROWS), 256, 0, stream>>>(X, emb, pos, h0, mb);
    dim3 g768(DMODEL / 64, ROWS / 64);
    dim3 g3072(DFF / 64, ROWS / 64);
    gemm64<DMODEL, 0><<<g768, 256, 0, stream>>>(h0, Wq, qb, DMODEL);
    gemm64<DMODEL, 0><<<g768, 256, 0, stream>>>(h0, Wk, kb, DMODEL);
    gemm64<DMODEL, 0><<<g768, 256, 0, stream>>>(h0, Wv, vb, DMODEL);
    enc_attn<<<dim3(BB * HN * SS), 64, 0, stream>>>(qb, kb, vb, mb, attc);
    gemm64<DMODEL, 0><<<g768, 256, 0, stream>>>(attc, Wo, attp, DMODEL);
    lnresP<1><<<dim3(ROWS), 256, 0, stream>>>(h0, attp, h1, nullptr, 0, 0);
    gemm64<DMODEL, 1><<<g3072, 256, 0, stream>>>(h1, W1, ff1, DFF);
    gemm64<DFF, 0><<<g768, 256, 0, stream>>>(ff1, W2, ff2, DMODEL);
    lnresP<1><<<dim3(ROWS), 256, 0, stream>>>(h1, ff2, memb, nullptr, 0, 0);
    gemm64<DMODEL, 0><<<g768, 256, 0, stream>>>(memb, Wdk, Kmem, DMODEL);
    gemm64<DMODEL, 0><<<g768, 256, 0, stream>>>(memb, Wdv, Vmem, DMODEL);

    // ---- beam search decode ----
    for (int t = 0; t < TT; t++) {
        embed_dec<<<dim3(32), 256, 0, stream>>>(tokens, emb, pos, t, x, xT);
        skinny2<192, 0, 0><<<dim3(12, 4), 256, 0, stream>>>(xT, Wdq, qdp, DMODEL);
        dec_attn<<<dim3(BB * KW * HN), 64, 0, stream>>>(qdp, Kmem, Vmem, mb, cctxT);
        skinny2<192, 0, 0><<<dim3(12, 4), 256, 0, stream>>>(cctxT, Wdo, cprojp, DMODEL);
        lnresP<4><<<dim3(32), 256, 0, stream>>>(x, cprojp, hd1, hd1T, 1, (int)P32);
        skinny2<768, 1, 1><<<dim3(48, 1), 256, 0, stream>>>(hd1T, Wd1, dff1T, DFF);
        skinny2<768, 0, 0><<<dim3(12, 4), 256, 0, stream>>>(dff1T, Wd2, dff2p, DMODEL);
        lnresP<4><<<dim3(32), 256, 0, stream>>>(hd1, dff2p, hd2, hd2T, 1, (int)P32);
        logits_stats<<<dim3(CHN), 256, 0, stream>>>(hd2T, Wvoc, cmax, csum, ctv, cti);
        merge_topk<<<dim3(BB), 256, 0, stream>>>(cmax, csum, ctv, cti,
                                                 scores, tokens, beamh, tokh, t);
    }

    backtrack_k<<<1, 64, 0, stream>>>(beamh, tokh, scores, (float*)d_out);
}

// Round 3
// 9357.498 us; speedup vs baseline: 4.8847x; 1.5110x over previous
//
#include <hip/hip_runtime.h>
#include <math.h>

#define DMODEL 768
#define HN 12
#define DHEAD 64
#define DFF 3072
#define VOC 30522
#define BB 8
#define SS 128
#define KW 4
#define TT 32
#define CHN 239   // ceil(30522/128)

__device__ __forceinline__ float gelu_f(float x) {
    float x3 = x * x * x;
    return 0.5f * x * (1.0f + tanhf(0.7978845608028654f * (x + 0.044715f * x3)));
}

// ---- init tokens/scores ----
__global__ void init_k(int* tokens, float* scores) {
    int i = threadIdx.x;
    if (i < BB * KW) {
        tokens[i] = 101;                      // BOS
        scores[i] = (i & 3) ? -1e9f : 0.0f;
    }
}

// ---- h = emb[X] + pos[:S]; mb = (X!=0)?0:-1e9 ----
__global__ __launch_bounds__(256) void embed_enc(const int* __restrict__ X,
                                                 const float* __restrict__ emb,
                                                 const float* __restrict__ pos,
                                                 float* __restrict__ h,
                                                 float* __restrict__ mb) {
    int row = blockIdx.x;
    int s = row & (SS - 1);
    int tok = X[row];
    const float* e = emb + (size_t)tok * DMODEL;
    const float* p = pos + (size_t)s * DMODEL;
    float* hp = h + (size_t)row * DMODEL;
    for (int c = threadIdx.x; c < DMODEL; c += 256) hp[c] = e[c] + p[c];
    if (threadIdx.x == 0) mb[row] = (tok != 0) ? 0.0f : -1e9f;
}

// ---- f32 GEMM 64x64 tile, register-prefetch double-buffered staging ----
template<int KD, int ACT>
__global__ __launch_bounds__(256) void gemm64(const float* __restrict__ A,
                                              const float* __restrict__ B,
                                              float* __restrict__ C, int N) {
    __shared__ float As[16][68];
    __shared__ float Bs[16][68];
    int tid = threadIdx.x;
    int tx = tid & 15, ty = tid >> 4;
    int bm = blockIdx.y * 64, bn = blockIdx.x * 64;
    int a_gk = tid & 15, a_gm0 = tid >> 4;
    int b_gn = tid & 63, b_gk0 = tid >> 6;
    float ra[4], rb[4];
    float acc[4][4] = {};
#pragma unroll
    for (int p = 0; p < 4; p++) ra[p] = A[(size_t)(bm + a_gm0 + p * 16) * KD + a_gk];
#pragma unroll
    for (int p = 0; p < 4; p++) rb[p] = B[(size_t)(b_gk0 + p * 4) * N + bn + b_gn];
    for (int k0 = 0; k0 < KD; k0 += 16) {
        __syncthreads();
#pragma unroll
        for (int p = 0; p < 4; p++) As[a_gk][a_gm0 + p * 16] = ra[p];
#pragma unroll
        for (int p = 0; p < 4; p++) Bs[b_gk0 + p * 4][b_gn] = rb[p];
        __syncthreads();
        if (k0 + 16 < KD) {
#pragma unroll
            for (int p = 0; p < 4; p++) ra[p] = A[(size_t)(bm + a_gm0 + p * 16) * KD + k0 + 16 + a_gk];
#pragma unroll
            for (int p = 0; p < 4; p++) rb[p] = B[(size_t)(k0 + 16 + b_gk0 + p * 4) * N + bn + b_gn];
        }
#pragma unroll
        for (int kk = 0; kk < 16; kk++) {
            float4 a4 = *(const float4*)&As[kk][ty * 4];
            float4 b4 = *(const float4*)&Bs[kk][tx * 4];
            float av[4] = {a4.x, a4.y, a4.z, a4.w};
            float bv[4] = {b4.x, b4.y, b4.z, b4.w};
#pragma unroll
            for (int i = 0; i < 4; i++)
#pragma unroll
                for (int j = 0; j < 4; j++) acc[i][j] += av[i] * bv[j];
        }
    }
#pragma unroll
    for (int i = 0; i < 4; i++)
#pragma unroll
        for (int j = 0; j < 4; j++) {
            float v = acc[i][j];
            if (ACT) v = gelu_f(v);
            C[(size_t)(bm + ty * 4 + i) * N + bn + tx * 4 + j] = v;
        }
}

// ---- encoder self-attention: one block (64 thr) per (b,h,q) ----
__global__ __launch_bounds__(64) void enc_attn(const float* __restrict__ q,
                                               const float* __restrict__ k,
                                               const float* __restrict__ v,
                                               const float* __restrict__ mb,
                                               float* __restrict__ ctx) {
    int bid = blockIdx.x;
    int qi = bid & (SS - 1);
    int h = (bid >> 7) % HN;
    int b = bid / (SS * HN);
    int lane = threadIdx.x;
    __shared__ float qs[DHEAD];
    __shared__ float att[SS];
    qs[lane] = q[((size_t)(b * SS + qi) * HN + h) * DHEAD + lane];
    __syncthreads();
    const float* kb = k + ((size_t)(b * SS) * HN + h) * DHEAD;
    const float* k0p = kb + (size_t)lane * DMODEL;
    const float* k1p = kb + (size_t)(lane + 64) * DMODEL;
    float s0 = 0.f, s1 = 0.f;
#pragma unroll 8
    for (int d = 0; d < DHEAD; d++) {
        float qd = qs[d];
        s0 += qd * k0p[d];
        s1 += qd * k1p[d];
    }
    s0 = s0 * 0.125f + mb[b * SS + lane];
    s1 = s1 * 0.125f + mb[b * SS + lane + 64];
    float m = fmaxf(s0, s1);
    for (int off = 32; off; off >>= 1) m = fmaxf(m, __shfl_xor(m, off, 64));
    float e0 = expf(s0 - m), e1 = expf(s1 - m);
    float sum = e0 + e1;
    for (int off = 32; off; off >>= 1) sum += __shfl_xor(sum, off, 64);
    float inv = 1.0f / sum;
    att[lane] = e0 * inv;
    att[lane + 64] = e1 * inv;
    __syncthreads();
    const float* vb = v + ((size_t)(b * SS) * HN + h) * DHEAD + lane;
    float acc = 0.f;
#pragma unroll 8
    for (int key = 0; key < SS; key++) acc += att[key] * vb[(size_t)key * DMODEL];
    ctx[(size_t)(b * SS + qi) * DMODEL + h * DHEAD + lane] = acc;
}

// ---- out = LN(A + sum_p Bsrc[p]); optional transposed copy (32-row only) ----
template<int P>
__global__ __launch_bounds__(256) void lnresP(const float* __restrict__ A,
                                              const float* __restrict__ Bsrc,
                                              float* __restrict__ out,
                                              float* __restrict__ outT,
                                              int wantT, int planeStride) {
    int row = blockIdx.x, tid = threadIdx.x;
    const float* ap = A + (size_t)row * DMODEL;
    float x[3];
#pragma unroll
    for (int i = 0; i < 3; i++) {
        int idx = tid + 256 * i;
        float s = ap[idx];
#pragma unroll
        for (int p = 0; p < P; p++) s += Bsrc[(size_t)p * planeStride + (size_t)row * DMODEL + idx];
        x[i] = s;
    }
    __shared__ float red[256];
    __shared__ float sm, sv;
    red[tid] = x[0] + x[1] + x[2];
    __syncthreads();
    for (int off = 128; off; off >>= 1) { if (tid < off) red[tid] += red[tid + off]; __syncthreads(); }
    if (tid == 0) sm = red[0] * (1.0f / DMODEL);
    __syncthreads();
    float mean = sm;
    float d[3], s2 = 0.f;
#pragma unroll
    for (int i = 0; i < 3; i++) { d[i] = x[i] - mean; s2 += d[i] * d[i]; }
    __syncthreads();
    red[tid] = s2;
    __syncthreads();
    for (int off = 128; off; off >>= 1) { if (tid < off) red[tid] += red[tid + off]; __syncthreads(); }
    if (tid == 0) sv = 1.0f / sqrtf(red[0] * (1.0f / DMODEL) + 1e-5f);
    __syncthreads();
    float inv = sv;
    float* op = out + (size_t)row * DMODEL;
#pragma unroll
    for (int i = 0; i < 3; i++) {
        float val = d[i] * inv;
        op[tid + 256 * i] = val;
        if (wantT) outT[(size_t)(tid + 256 * i) * 32 + row] = val;
    }
}

// ---- x = emb[tokens] + pos[t]; also xT ----
__global__ __launch_bounds__(256) void embed_dec(const int* __restrict__ tokens,
                                                 const float* __restrict__ emb,
                                                 const float* __restrict__ pos,
                                                 int t, float* __restrict__ x,
                                                 float* __restrict__ xT) {
    int row = blockIdx.x;
    int tok = tokens[row];
    const float* e = emb + (size_t)tok * DMODEL;
    const float* p = pos + (size_t)t * DMODEL;
    for (int c = threadIdx.x; c < DMODEL; c += 256) {
        float v = e[c] + p[c];
        x[(size_t)row * DMODEL + c] = v;
        xT[(size_t)c * 32 + row] = v;
    }
}

// ---- skinny GEMM v3: wave owns 8 rows, lane owns 2 cols. ----
// A layout [Ktot][32] (optionally APL partial planes summed w/ gelu at staging).
// Block (x) covers 128 cols; block (y) covers KRANGE k's; output plane y.
// TOUT=1 -> C[col*32+row] per plane; else C[row*N+col].
template<int KRANGE, int APL, int AGELU, int TOUT>
__global__ __launch_bounds__(256) void skinny3(const float* __restrict__ At,
                                               const float* __restrict__ B,
                                               float* __restrict__ C,
                                               int N, int aPlaneF4) {
    constexpr int SK = (KRANGE > 192) ? 192 : KRANGE;
    constexpr int NST = KRANGE / SK;
    __shared__ float Als[SK * 32];
    int tid = threadIdx.x;
    int lane = tid & 63, q = tid >> 6;
    int col0 = blockIdx.x * 128 + lane * 2;
    float acc[8][2] = {};
    for (int st = 0; st < NST; st++) {
        int kbase = blockIdx.y * KRANGE + st * SK;
        __syncthreads();
        const float4* srcb = ((const float4*)At) + (size_t)kbase * 8;
        float4* dst = (float4*)Als;
#pragma unroll
        for (int i = 0; i < SK / 32; i++) {
            float4 v = srcb[i * 256 + tid];
#pragma unroll
            for (int p = 1; p < APL; p++) {
                float4 w = srcb[(size_t)p * aPlaneF4 + i * 256 + tid];
                v.x += w.x; v.y += w.y; v.z += w.z; v.w += w.w;
            }
            if (AGELU) { v.x = gelu_f(v.x); v.y = gelu_f(v.y); v.z = gelu_f(v.z); v.w = gelu_f(v.w); }
            dst[i * 256 + tid] = v;
        }
        __syncthreads();
        const float* Bp = B + (size_t)kbase * N + col0;
#pragma unroll 8
        for (int k = 0; k < SK; k++) {
            float2 bv = *(const float2*)(Bp + (size_t)k * N);
            float4 a0 = *(const float4*)&Als[k * 32 + q * 8];
            float4 a1 = *(const float4*)&Als[k * 32 + q * 8 + 4];
            float ar[8] = {a0.x, a0.y, a0.z, a0.w, a1.x, a1.y, a1.z, a1.w};
#pragma unroll
            for (int r = 0; r < 8; r++) {
                acc[r][0] += ar[r] * bv.x;
                acc[r][1] += ar[r] * bv.y;
            }
        }
    }
    float* Cb = C + (size_t)blockIdx.y * 32 * N;
    if (TOUT) {
#pragma unroll
        for (int c = 0; c < 2; c++) {
            float4 lo = {acc[0][c], acc[1][c], acc[2][c], acc[3][c]};
            float4 hi = {acc[4][c], acc[5][c], acc[6][c], acc[7][c]};
            *(float4*)&Cb[(size_t)(col0 + c) * 32 + q * 8] = lo;
            *(float4*)&Cb[(size_t)(col0 + c) * 32 + q * 8 + 4] = hi;
        }
    } else {
#pragma unroll
        for (int r = 0; r < 8; r++) {
            float2 st2 = {acc[r][0], acc[r][1]};
            *(float2*)&Cb[(size_t)(q * 8 + r) * N + col0] = st2;
        }
    }
}

// ---- decoder cross-attn; qd given as 8 k-split partial planes ----
__global__ __launch_bounds__(64) void dec_attn(const float* __restrict__ qdp,
                                               const float* __restrict__ Kmem,
                                               const float* __restrict__ Vmem,
                                               const float* __restrict__ mb,
                                               float* __restrict__ cctxT) {
    const int QP = 32 * DMODEL;
    int bid = blockIdx.x;
    int h = bid % HN;
    int kb = (bid / HN) & 3;
    int b = bid / (HN * KW);
    int lane = threadIdx.x;
    int rowq = b * KW + kb;
    __shared__ float qs[DHEAD];
    __shared__ float att[SS];
    size_t qoff = (size_t)rowq * DMODEL + h * DHEAD + lane;
    float qv = 0.f;
#pragma unroll
    for (int p = 0; p < 8; p++) qv += qdp[(size_t)p * QP + qoff];
    qs[lane] = qv;
    __syncthreads();
    const float* kb0 = Kmem + ((size_t)(b * SS) * HN + h) * DHEAD;
    const float* k0p = kb0 + (size_t)lane * DMODEL;
    const float* k1p = kb0 + (size_t)(lane + 64) * DMODEL;
    float s0 = 0.f, s1 = 0.f;
#pragma unroll 8
    for (int d = 0; d < DHEAD; d++) {
        float qd = qs[d];
        s0 += qd * k0p[d];
        s1 += qd * k1p[d];
    }
    s0 = s0 * 0.125f + mb[b * SS + lane];
    s1 = s1 * 0.125f + mb[b * SS + lane + 64];
    float m = fmaxf(s0, s1);
    for (int off = 32; off; off >>= 1) m = fmaxf(m, __shfl_xor(m, off, 64));
    float e0 = expf(s0 - m), e1 = expf(s1 - m);
    float sum = e0 + e1;
    for (int off = 32; off; off >>= 1) sum += __shfl_xor(sum, off, 64);
    float inv = 1.0f / sum;
    att[lane] = e0 * inv;
    att[lane + 64] = e1 * inv;
    __syncthreads();
    const float* vb = Vmem + ((size_t)(b * SS) * HN + h) * DHEAD + lane;
    float acc = 0.f;
#pragma unroll 8
    for (int key = 0; key < SS; key++) acc += att[key] * vb[(size_t)key * DMODEL];
    cctxT[(size_t)(h * DHEAD + lane) * 32 + rowq] = acc;
}

// ---- logits chunk kernel: 128 cols/block, wave owns 8 rows, stats via shuffles ----
__global__ __launch_bounds__(256) void logits_stats(const float* __restrict__ At,   // hd2T [768][32]
                                                    const float* __restrict__ B,    // Wvoc
                                                    float* __restrict__ cmax,
                                                    float* __restrict__ csum,
                                                    float* __restrict__ ctv,
                                                    int* __restrict__ cti) {
    __shared__ float Als[192 * 32];
    int tid = threadIdx.x;
    int lane = tid & 63, q = tid >> 6;
    int col0 = blockIdx.x * 128 + lane * 2;
    bool valid = col0 < VOC;
    int jc = valid ? col0 : VOC - 2;
    float acc[8][2] = {};
    for (int st = 0; st < 4; st++) {
        int kbase = st * 192;
        __syncthreads();
        const float4* srcb = ((const float4*)At) + (size_t)kbase * 8;
        float4* dst = (float4*)Als;
#pragma unroll
        for (int i = 0; i < 6; i++) dst[i * 256 + tid] = srcb[i * 256 + tid];
        __syncthreads();
        const float* Bp = B + (size_t)kbase * VOC + jc;
#pragma unroll 8
        for (int k = 0; k < 192; k++) {
            float2 bv = *(const float2*)(Bp + (size_t)k * VOC);
            float4 a0 = *(const float4*)&Als[k * 32 + q * 8];
            float4 a1 = *(const float4*)&Als[k * 32 + q * 8 + 4];
            float ar[8] = {a0.x, a0.y, a0.z, a0.w, a1.x, a1.y, a1.z, a1.w};
#pragma unroll
            for (int r = 0; r < 8; r++) {
                acc[r][0] += ar[r] * bv.x;
                acc[r][1] += ar[r] * bv.y;
            }
        }
    }
    // per-row stats across the wave (row = q*8+r), 128 cols in regs
#pragma unroll 1
    for (int r = 0; r < 8; r++) {
        float v0 = valid ? acc[r][0] : -INFINITY;
        float v1 = valid ? acc[r][1] : -INFINITY;
        float mx = fmaxf(v0, v1);
#pragma unroll
        for (int off = 32; off; off >>= 1) mx = fmaxf(mx, __shfl_xor(mx, off, 64));
        float ss = valid ? (expf(v0 - mx) + expf(v1 - mx)) : 0.0f;
#pragma unroll
        for (int off = 32; off; off >>= 1) ss += __shfl_xor(ss, off, 64);
        float c0 = v0, c1 = v1;
        int i0 = col0, i1 = col0 + 1;
        float tv[4]; int ti[4];
#pragma unroll
        for (int p = 0; p < 4; p++) {
            float bv; int bi;
            if (c0 > c1 || (c0 == c1 && i0 < i1)) { bv = c0; bi = i0; } else { bv = c1; bi = i1; }
#pragma unroll
            for (int off = 32; off; off >>= 1) {
                float ov = __shfl_xor(bv, off, 64);
                int oi = __shfl_xor(bi, off, 64);
                if (ov > bv || (ov == bv && oi < bi)) { bv = ov; bi = oi; }
            }
            if (bi == i0) c0 = -INFINITY;
            else if (bi == i1) c1 = -INFINITY;
            tv[p] = bv; ti[p] = bi;
        }
        if (lane == 0) {
            int m = q * 8 + r;
            int o = m * CHN + blockIdx.x;
            cmax[o] = mx; csum[o] = ss;
            ctv[o * 4 + 0] = tv[0]; cti[o * 4 + 0] = ti[0];
            ctv[o * 4 + 1] = tv[1]; cti[o * 4 + 1] = ti[1];
            ctv[o * 4 + 2] = tv[2]; cti[o * 4 + 2] = ti[2];
            ctv[o * 4 + 3] = tv[3]; cti[o * 4 + 3] = ti[3];
        }
    }
}

// ---- merge chunk stats: wave q = beam q; shuffle reductions; final serial merge ----
__global__ __launch_bounds__(256) void merge_topk(const float* __restrict__ cmax,
                                                  const float* __restrict__ csum,
                                                  const float* __restrict__ ctv,
                                                  const int* __restrict__ cti,
                                                  float* scores, int* tokens,
                                                  int* beamh, int* tokh, int t) {
    int b = blockIdx.x, tid = threadIdx.x;
    int lane = tid & 63, q = tid >> 6;
    int m = b * 4 + q;
    __shared__ float LSE[4], s_old[4];
    __shared__ float bt_v[4][4];
    __shared__ int bt_i[4][4];
    if (tid < 4) s_old[tid] = scores[b * 4 + tid];
    // ---- LSE over chunks (online softmax merge) ----
    float mx = -INFINITY, sm = 0.f;
    for (int c = lane; c < CHN; c += 64) {
        float cm = cmax[m * CHN + c], cs = csum[m * CHN + c];
        if (cm > mx) { sm = sm * expf(mx - cm) + cs; mx = cm; }
        else sm += cs * expf(cm - mx);
    }
#pragma unroll
    for (int off = 32; off; off >>= 1) {
        float om = __shfl_xor(mx, off, 64);
        float os = __shfl_xor(sm, off, 64);
        float M = fmaxf(mx, om);
        sm = sm * expf(mx - M) + os * expf(om - M);
        mx = M;
    }
    if (lane == 0) LSE[q] = mx + logf(sm);
    // ---- local top-4 (sorted by val desc, idx asc) ----
    float lv[4] = {-INFINITY, -INFINITY, -INFINITY, -INFINITY};
    int li[4] = {0x7fffffff, 0x7fffffff, 0x7fffffff, 0x7fffffff};
    for (int c = lane; c < CHN; c += 64) {
        int o = (m * CHN + c) * 4;
#pragma unroll
        for (int j = 0; j < 4; j++) {
            float v = ctv[o + j]; int i = cti[o + j];
            if (v > lv[3] || (v == lv[3] && i < li[3])) {
                lv[3] = v; li[3] = i;
#pragma unroll
                for (int s = 3; s > 0; s--) {
                    if (lv[s] > lv[s - 1] || (lv[s] == lv[s - 1] && li[s] < li[s - 1])) {
                        float tv2 = lv[s]; lv[s] = lv[s - 1]; lv[s - 1] = tv2;
                        int ti2 = li[s]; li[s] = li[s - 1]; li[s - 1] = ti2;
                    }
                }
            }
        }
    }
    // ---- 4 passes of wave argmax with pop ----
#pragma unroll
    for (int p = 0; p < 4; p++) {
        float bv = lv[0]; int bi = li[0];
#pragma unroll
        for (int off = 32; off; off >>= 1) {
            float ov = __shfl_xor(bv, off, 64);
            int oi = __shfl_xor(bi, off, 64);
            if (ov > bv || (ov == bv && oi < bi)) { bv = ov; bi = oi; }
        }
        if (li[0] == bi) {
            lv[0] = lv[1]; li[0] = li[1];
            lv[1] = lv[2]; li[1] = li[2];
            lv[2] = lv[3]; li[2] = li[3];
            lv[3] = -INFINITY; li[3] = 0x7fffffff;
        }
        if (lane == 0) { bt_v[q][p] = bv; bt_i[q][p] = bi; }
    }
    __syncthreads();
    // ---- final cross-beam merge (exact, serial) ----
    if (tid == 0) {
        float fv[16]; int fi[16]; bool used[16];
#pragma unroll
        for (int r = 0; r < 4; r++)
#pragma unroll
            for (int p = 0; p < 4; p++) {
                fv[r * 4 + p] = s_old[r] - LSE[r] + bt_v[r][p];
                fi[r * 4 + p] = r * VOC + bt_i[r][p];
                used[r * 4 + p] = false;
            }
        for (int kk = 0; kk < 4; kk++) {
            int best = -1;
            for (int c2 = 0; c2 < 16; c2++) {
                if (used[c2]) continue;
                if (best < 0 || fv[c2] > fv[best] || (fv[c2] == fv[best] && fi[c2] < fi[best])) best = c2;
            }
            used[best] = true;
            int beam = fi[best] / VOC;
            int tok = fi[best] - beam * VOC;
            scores[b * 4 + kk] = fv[best];
            tokens[b * 4 + kk] = tok;
            beamh[(t * BB + b) * 4 + kk] = beam;
            tokh[(t * BB + b) * 4 + kk] = tok;
        }
    }
}

// ---- backtrack ----
__global__ void backtrack_k(const int* __restrict__ beamh, const int* __restrict__ tokh,
                            const float* __restrict__ scores, float* __restrict__ out) {
    int i = threadIdx.x;
    if (i < BB * KW) {
        int b = i >> 2, k = i & 3;
        int ptr = k;
        for (int t = TT - 1; t >= 0; t--) {
            int tok = tokh[(t * BB + b) * KW + ptr];
            out[(size_t)i * TT + t] = (float)tok;
            ptr = beamh[(t * BB + b) * KW + ptr];
        }
        out[BB * KW * TT + i] = scores[i];
    }
}

extern "C" void kernel_launch(void* const* d_in, const int* in_sizes, int n_in,
                              void* d_out, int out_size, void* d_ws, size_t ws_size,
                              hipStream_t stream) {
    const int* X = (const int*)d_in[0];
    const float* emb = (const float*)d_in[1];
    const float* pos = (const float*)d_in[2];
    const float* Wq = (const float*)d_in[3];
    const float* Wk = (const float*)d_in[4];
    const float* Wv = (const float*)d_in[5];
    const float* Wo = (const float*)d_in[6];
    const float* W1 = (const float*)d_in[7];
    const float* W2 = (const float*)d_in[8];
    const float* Wdq = (const float*)d_in[9];
    const float* Wdk = (const float*)d_in[10];
    const float* Wdv = (const float*)d_in[11];
    const float* Wdo = (const float*)d_in[12];
    const float* Wd1 = (const float*)d_in[13];
    const float* Wd2 = (const float*)d_in[14];
    const float* Wvoc = (const float*)d_in[15];

    float* ws = (float*)d_ws;
    size_t o = 0;
    auto alloc = [&](size_t n) { float* p = ws + o; o += n; return p; };

    const size_t ROWS = (size_t)BB * SS;       // 1024
    const size_t HD = ROWS * DMODEL;
    const size_t P32 = 32 * DMODEL;            // 24576

    // persistent
    float* mb = alloc(ROWS);
    float* Kmem = alloc(HD);
    float* Vmem = alloc(HD);
    float* scores = alloc(32);
    int* tokens = (int*)alloc(32);
    int* beamh = (int*)alloc(TT * BB * KW);
    int* tokh = (int*)alloc(TT * BB * KW);

    size_t mark = o;
    // encoder scratch
    float* h0 = alloc(HD);
    float* qb = alloc(HD);
    float* kb = alloc(HD);
    float* vb = alloc(HD);
    float* attc = alloc(HD);
    float* attp = alloc(HD);
    float* h1 = alloc(HD);
    float* ff1 = alloc(ROWS * DFF);
    float* ff2 = alloc(HD);
    float* memb = alloc(HD);

    // decoder scratch (aliases encoder scratch)
    o = mark;
    float* x = alloc(P32);
    float* xT = alloc(P32);
    float* qdp = alloc(8 * P32);
    float* cctxT = alloc(P32);
    float* cprojp = alloc(8 * P32);
    float* hd1 = alloc(P32);
    float* hd1T = alloc(P32);
    float* dff1p = alloc((size_t)4 * DFF * 32);
    float* dff2p = alloc(8 * P32);
    float* hd2 = alloc(P32);
    float* hd2T = alloc(P32);
    float* cmax = alloc(32 * CHN);
    float* csum = alloc(32 * CHN);
    float* ctv = alloc((size_t)32 * CHN * 4);
    int* cti = (int*)alloc((size_t)32 * CHN * 4);
    (void)ws_size; (void)in_sizes; (void)n_in; (void)out_size;

    init_k<<<1, 64, 0, stream>>>(tokens, scores);

    // ---- encoder ----
    embed_enc<<<dim3(ROWS), 256, 0, stream>>>(X, emb, pos, h0, mb);
    dim3 g768(DMODEL / 64, ROWS / 64);
    dim3 g3072(DFF / 64, ROWS / 64);
    gemm64<DMODEL, 0><<<g768, 256, 0, stream>>>(h0, Wq, qb, DMODEL);
    gemm64<DMODEL, 0><<<g768, 256, 0, stream>>>(h0, Wk, kb, DMODEL);
    gemm64<DMODEL, 0><<<g768, 256, 0, stream>>>(h0, Wv, vb, DMODEL);
    enc_attn<<<dim3(BB * HN * SS), 64, 0, stream>>>(qb, kb, vb, mb, attc);
    gemm64<DMODEL, 0><<<g768, 256, 0, stream>>>(attc, Wo, attp, DMODEL);
    lnresP<1><<<dim3(ROWS), 256, 0, stream>>>(h0, attp, h1, nullptr, 0, 0);
    gemm64<DMODEL, 1><<<g3072, 256, 0, stream>>>(h1, W1, ff1, DFF);
    gemm64<DFF, 0><<<g768, 256, 0, stream>>>(ff1, W2, ff2, DMODEL);
    lnresP<1><<<dim3(ROWS), 256, 0, stream>>>(h1, ff2, memb, nullptr, 0, 0);
    gemm64<DMODEL, 0><<<g768, 256, 0, stream>>>(memb, Wdk, Kmem, DMODEL);
    gemm64<DMODEL, 0><<<g768, 256, 0, stream>>>(memb, Wdv, Vmem, DMODEL);

    // ---- beam search decode ----
    for (int t = 0; t < TT; t++) {
        embed_dec<<<dim3(32), 256, 0, stream>>>(tokens, emb, pos, t, x, xT);
        skinny3<96, 1, 0, 0><<<dim3(6, 8), 256, 0, stream>>>(xT, Wdq, qdp, DMODEL, 0);
        dec_attn<<<dim3(BB * KW * HN), 64, 0, stream>>>(qdp, Kmem, Vmem, mb, cctxT);
        skinny3<96, 1, 0, 0><<<dim3(6, 8), 256, 0, stream>>>(cctxT, Wdo, cprojp, DMODEL, 0);
        lnresP<8><<<dim3(32), 256, 0, stream>>>(x, cprojp, hd1, hd1T, 1, (int)P32);
        skinny3<192, 1, 0, 1><<<dim3(24, 4), 256, 0, stream>>>(hd1T, Wd1, dff1p, DFF, 0);
        skinny3<384, 4, 1, 0><<<dim3(6, 8), 256, 0, stream>>>(dff1p, Wd2, dff2p, DMODEL, DFF * 8);
        lnresP<8><<<dim3(32), 256, 0, stream>>>(hd1, dff2p, hd2, hd2T, 1, (int)P32);
        logits_stats<<<dim3(CHN), 256, 0, stream>>>(hd2T, Wvoc, cmax, csum, ctv, cti);
        merge_topk<<<dim3(BB), 256, 0, stream>>>(cmax, csum, ctv, cti,
                                                 scores, tokens, beamh, tokh, t);
    }

    backtrack_k<<<1, 64, 0, stream>>>(beamh, tokh, scores, (float*)d_out);
}